// Round 5
// baseline (161.078 us; speedup 1.0000x reference)
//
#include <hip/hip_runtime.h>

// Gridding R10: R9 (159.9 µs) + x-range early-skip in p2's decode loop.
//   R9 counters: p2 = 67.2 µs = 65.6k u64 lane-atomics/CU x 2.45 cyc — the
//   LDS atomic pipe IS the clock; only VALU bubbles between atomic issues
//   are compressible (floor ~2 cyc/lane => <= ~12 µs headroom). Each bucket
//   is decoded by both half-blocks but ~45% of decoded points have no
//   x-corner in a given half — yet still burn ~15-20 VALU ops reaching the
//   per-corner checks. Fix: decode ux first, test ix in [x0-1, x0+1]
//   (unsigned one-compare), continue before any weight math. ~8 µs of VALU
//   pressure removed at 3 instructions' cost. Everything else identical to
//   the passing R9 (p1 = R7 form; prefetch-8; scnt cache; rescan healing).

#define NPTS   65536
#define NCHUNK 32
#define CHSZ   2048
#define NSLAB  16                  // p1 bucket slabs (4 planes)
#define SLABW  4
#define CCAP   256
#define SLOTS  (NCHUNK * CCAP)     // 8192 slots per bucket
#define ACCN   16384               // 2 planes * 64 * 64 u32 per accumulator
#define QSCALE 262144.0f           // 2^18 weight quant
#define QINV   (1.0f / 262144.0f)
#define CMASK  0x1FFFFFu           // 21-bit coordinate field
#define FSCALE 32768.0f            // 2^15 coordinate quant
#define FINV   (1.0f / 32768.0f)

// ---------------- Phase 1: identical to R7/R9 ----------------
__global__ __launch_bounds__(512) void p1_bin(
    const float* __restrict__ pt,
    unsigned long long* __restrict__ gp,
    int* __restrict__ bcnt)
{
    __shared__ unsigned long long spk[NSLAB * CCAP];   // 32 KB
    __shared__ int cnt[NSLAB];
    if (threadIdx.x < NSLAB) cnt[threadIdx.x] = 0;
    __syncthreads();

    const int blk = blockIdx.x;
    const int b = blk >> 5;
    const int c = blk & 31;
    const float* p = pt + ((size_t)b * NPTS + (size_t)c * CHSZ) * 3;

    #pragma unroll
    for (int k = 0; k < CHSZ / 512; ++k) {
        int li = k * 512 + threadIdx.x;
        float px = p[3 * li + 0] * 32.0f;
        float py = p[3 * li + 1] * 32.0f;
        float pz = p[3 * li + 2] * 32.0f;
        if (fabsf(px) + fabsf(py) + fabsf(pz) == 0.0f) continue;
        // grid-space [0,64) fixed point, round-to-nearest, clamped to the
        // 21-bit field (prevents cross-field carry for boundary values).
        unsigned ux = min(__float2uint_rn((px + 32.0f) * FSCALE), CMASK);
        unsigned uy = min(__float2uint_rn((py + 32.0f) * FSCALE), CMASK);
        unsigned uz = min(__float2uint_rn((pz + 32.0f) * FSCALE), CMASK);
        int ix = (int)(ux >> 15);            // 0..63 by construction
        unsigned long long pk =
            (unsigned long long)ux | ((unsigned long long)uy << 21)
                                   | ((unsigned long long)uz << 42);
        int s0 = ix >> 2;
        int pos = atomicAdd(&cnt[s0], 1);
        if (pos < CCAP) spk[s0 * CCAP + pos] = pk;
        if ((ix & 3) == 3 && ix < 63) {
            int pos1 = atomicAdd(&cnt[s0 + 1], 1);
            if (pos1 < CCAP) spk[(s0 + 1) * CCAP + pos1] = pk;
        }
    }
    __syncthreads();

    // Flush only the counted slots (garbage slots never touch HBM).
    #pragma unroll
    for (int i = threadIdx.x; i < NSLAB * CCAP; i += 512) {
        int s = i >> 8, e = i & 255;
        if (e < min(cnt[s], CCAP)) {
            size_t d = ((size_t)((b * NSLAB + s) * NCHUNK + c)) * CCAP + e;
            gp[d] = spk[i];
        }
    }
    if (threadIdx.x < NSLAB)
        bcnt[(b * NSLAB + threadIdx.x) * NCHUNK + c] = min(cnt[threadIdx.x], CCAP);
}

// Shared corner accumulation (packed u64 LDS atomics), grid-space coords.
//   S[0..ACCN)      = A: cell (xl,y,z) at (xl*64+y)*64+z   (z-even u64 pairs)
//   S[ACCN..2*ACCN) = B: shifted pairs (z-odd), B[cb+z-1],B[cb+z]
__device__ __forceinline__ void accum_corners(
    unsigned int* S, int ix, int iy, int iz,
    float fx, float fy, float fz, int x0)
{
    if ((unsigned)iz > 63u) return;     // OOB z (garbage guard)

    float wx[2] = {1.0f - fx, fx};
    float wy[2] = {1.0f - fy, fy};
    float wz0 = 1.0f - fz, wz1 = fz;

    const int odd = iz & 1;
    const int zoff = odd ? (ACCN + iz - 1) : iz;   // both branches 8B-aligned
    const bool hi_ok = (iz != 63);                 // cell iz+1==64 OOB -> add 0

    #pragma unroll
    for (int di = 0; di < 2; ++di) {
        int xl = ix + di - x0;              // sub-slab-local x
        if ((unsigned)xl >= 2u) continue;
        #pragma unroll
        for (int dj = 0; dj < 2; ++dj) {
            int yy = iy + dj;
            if ((unsigned)yy >= 64u) continue;
            float wxy = wx[di] * wy[dj];
            unsigned int q0 = __float2uint_rn(wxy * wz0 * QSCALE);
            unsigned int q1 = hi_ok ? __float2uint_rn(wxy * wz1 * QSCALE) : 0u;
            int cb = (xl * 64 + yy) * 64;
            unsigned long long pk =
                (unsigned long long)q0 | ((unsigned long long)q1 << 32);
            atomicAdd((unsigned long long*)&S[cb + zoff], pk);  // ds_add_u64
        }
    }
}

// ---------------- Phase 2: 2-plane sub-slab, packed u64 LDS atomics -------
__global__ __launch_bounds__(1024) void p2_accum(
    const unsigned long long* __restrict__ gp, const int* __restrict__ bcnt,
    const float* __restrict__ pt, float* __restrict__ out)
{
    __shared__ unsigned int S[2 * ACCN];
    __shared__ int scnt[NCHUNK];
    __shared__ int rescan;

    const int pb = blockIdx.x >> 1;     // parent bucket (b*16 + s)
    const int h  = blockIdx.x & 1;      // which half of the 4-wide slab
    const int b  = pb >> 4;
    const int s  = pb & 15;
    const int x0 = s * SLABW + h * 2;   // my 2 planes: x0, x0+1

    if (threadIdx.x == 0) rescan = 0;
    if (threadIdx.x < NCHUNK)
        scnt[threadIdx.x] = bcnt[pb * NCHUNK + threadIdx.x];
    uint4* s4 = (uint4*)S;
    #pragma unroll
    for (int i = threadIdx.x; i < (2 * ACCN) / 4; i += 1024)
        s4[i] = make_uint4(0u, 0u, 0u, 0u);
    __syncthreads();

    // Saturation / sanity check: CCAP sentinel (p1 dropped points) or
    // garbage counts -> this block redoes its sub-slab from raw points.
    if (threadIdx.x < NCHUNK) {
        if ((unsigned)scnt[threadIdx.x] >= (unsigned)CCAP) rescan = 1;
    }
    __syncthreads();

    if (!rescan) {
        // ---- fast path: prefetch ALL 8 slots into registers, then
        //      decode+atomic with no exposed load latency.
        const size_t base = (size_t)pb * SLOTS;

        unsigned long long v[SLOTS / 1024];
        bool ok[SLOTS / 1024];
        #pragma unroll
        for (int i = 0; i < SLOTS / 1024; ++i) {
            int t = i * 1024 + threadIdx.x;
            v[i]  = gp[base + t];
            ok[i] = (t & 255) < scnt[t >> 8];
        }

        #pragma unroll
        for (int i = 0; i < SLOTS / 1024; ++i) {
            if (!ok[i]) continue;
            unsigned long long pk = v[i];
            unsigned ux = (unsigned)pk & CMASK;
            int ix = (int)(ux >> 15);
            // Early skip: corners {ix, ix+1} intersect {x0, x0+1} iff
            // ix in [x0-1, x0+1]. ~45% of decoded points fail -> skip
            // all weight math before it happens.
            if ((unsigned)(ix - x0 + 1) > 2u) continue;
            unsigned uy = (unsigned)(pk >> 21) & CMASK;
            unsigned uz = (unsigned)(pk >> 42) & CMASK;
            accum_corners(S, ix, (int)(uy >> 15), (int)(uz >> 15),
                          (float)(ux & 32767u) * FINV,
                          (float)(uy & 32767u) * FINV,
                          (float)(uz & 32767u) * FINV, x0);
        }
    } else {
        // ---- self-healing path: exclusive scan of batch b's raw points ----
        const float* p = pt + (size_t)b * NPTS * 3;
        for (int i = threadIdx.x; i < NPTS; i += 1024) {
            float px = p[3 * i + 0] * 32.0f;
            float py = p[3 * i + 1] * 32.0f;
            float pz = p[3 * i + 2] * 32.0f;
            if (fabsf(px) + fabsf(py) + fabsf(pz) == 0.0f) continue;
            float gxs = px + 32.0f, gys = py + 32.0f, gzs = pz + 32.0f;
            float lx = floorf(gxs), ly = floorf(gys), lz = floorf(gzs);
            int ix = (int)lx, iy = (int)ly, iz = (int)lz;
            if ((unsigned)ix > 63u) continue;   // match p1's binning filter
            accum_corners(S, ix, iy, iz, gxs - lx, gys - ly, gzs - lz, x0);
        }
    }
    __syncthreads();

    // Flush: cell i (= (xl*64+y)*64+z) = A[i] + (z>0 ? B[i-1] : 0), dequant.
    float* o = out + ((size_t)b * 64 + x0) * 4096;
    #pragma unroll
    for (int i = threadIdx.x; i < 2 * 4096; i += 1024) {
        int z = i & 63;
        unsigned int v2 = S[i] + (z ? S[ACCN + i - 1] : 0u);
        o[i] = (float)v2 * QINV;
    }
}

// ---- Fallback (exclusive-slab redundant scan) if workspace too small.
__global__ __launch_bounds__(1024) void gridding_slab(
    const float* __restrict__ pt, float* __restrict__ out)
{
    __shared__ float lds[SLABW * 64 * 64];
    const int blk = blockIdx.x;
    const int b   = blk >> 4;
    const int x0  = (blk & 15) * SLABW;
    float4* l4 = (float4*)lds;
    #pragma unroll
    for (int i = threadIdx.x; i < (SLABW * 64 * 64) / 4; i += 1024)
        l4[i] = make_float4(0.f, 0.f, 0.f, 0.f);
    __syncthreads();
    const float* p = pt + (size_t)b * NPTS * 3;
    for (int it = 0; it < NPTS / 1024; ++it) {
        int i = it * 1024 + threadIdx.x;
        float px = p[3 * i + 0] * 32.0f;
        float py = p[3 * i + 1] * 32.0f;
        float pz = p[3 * i + 2] * 32.0f;
        if (fabsf(px) + fabsf(py) + fabsf(pz) == 0.0f) continue;
        float lx = floorf(px), ly = floorf(py), lz = floorf(pz);
        float fx = px - lx, fy = py - ly, fz = pz - lz;
        int ix = (int)lx + 32, iy = (int)ly + 32, iz = (int)lz + 32;
        float wx[2] = {1.0f - fx, fx};
        float wy[2] = {1.0f - fy, fy};
        float wz[2] = {1.0f - fz, fz};
        #pragma unroll
        for (int di = 0; di < 2; ++di) {
            int xl = (ix + di) - x0;
            if ((unsigned)xl >= SLABW) continue;
            #pragma unroll
            for (int dj = 0; dj < 2; ++dj) {
                int yy = iy + dj;
                if ((unsigned)yy >= 64u) continue;
                float wxy = wx[di] * wy[dj];
                int basei = (xl * 64 + yy) * 64;
                #pragma unroll
                for (int dk = 0; dk < 2; ++dk) {
                    int zz = iz + dk;
                    if ((unsigned)zz >= 64u) continue;
                    atomicAdd(&lds[basei + zz], wxy * wz[dk]);
                }
            }
        }
    }
    __syncthreads();
    float4* o4 = (float4*)(out + ((size_t)b * 64 + x0) * 4096);
    #pragma unroll
    for (int i = threadIdx.x; i < (SLABW * 64 * 64) / 4; i += 1024)
        o4[i] = l4[i];
}

extern "C" void kernel_launch(void* const* d_in, const int* in_sizes, int n_in,
                              void* d_out, int out_size, void* d_ws, size_t ws_size,
                              hipStream_t stream) {
    const float* pt = (const float*)d_in[0];
    float* out = (float*)d_out;
    const int B = (in_sizes[0] / 3) / NPTS;   // 64

    const size_t nbuck = (size_t)B * NSLAB;           // 1024
    const size_t arr   = nbuck * SLOTS;
    const size_t need  = arr * sizeof(unsigned long long)
                       + nbuck * NCHUNK * sizeof(int);

    if (ws_size >= need) {
        unsigned long long* gp = (unsigned long long*)d_ws;
        int* bcnt = (int*)(gp + arr);
        p1_bin<<<B * NCHUNK, 512, 0, stream>>>(pt, gp, bcnt);
        p2_accum<<<(int)(nbuck * 2), 1024, 0, stream>>>(gp, bcnt, pt, out);
    } else {
        gridding_slab<<<B * NSLAB, 1024, 0, stream>>>(pt, out);
    }
}